// Round 6
// baseline (345.810 us; speedup 1.0000x reference)
//
#include <hip/hip_runtime.h>
#include <hip/hip_fp16.h>

// LFM2 short-conv block. Round 6: 256x256 GEMM, single-barrier 4-phase schedule,
// 32x32x16 MFMA (was 16x16x32 + 2 barriers/phase). Staging/swizzle/vmcnt ledger
// identical to the round-3/5 passing kernel.

typedef _Float16 f16x8  __attribute__((ext_vector_type(8)));
typedef float    f32x4  __attribute__((ext_vector_type(4)));
typedef float    f32x16 __attribute__((ext_vector_type(16)));

#define GLD_LDS16(gsrc, sdst) \
  __builtin_amdgcn_global_load_lds((const __attribute__((address_space(1))) void*)(gsrc), \
                                   (__attribute__((address_space(3))) void*)(sdst), 16, 0, 0)

#define VMCNT4 asm volatile("s_waitcnt vmcnt(4)" ::: "memory")
#define VMCNT0 asm volatile("s_waitcnt vmcnt(0)" ::: "memory")
#define LGKM0  asm volatile("s_waitcnt lgkmcnt(0)" ::: "memory")
#define BAR    __builtin_amdgcn_s_barrier()
#define SCHED0 __builtin_amdgcn_sched_barrier(0)

// ---------------- fp32 -> fp16 convert (8 elems/thread) ----------------
__global__ __launch_bounds__(256) void cvt_f32_f16(const float* __restrict__ in,
                                                   _Float16* __restrict__ out, int n) {
  int i = blockIdx.x * 256 + threadIdx.x;
  int base = i * 8;
  if (base >= n) return;
  const float4* p = reinterpret_cast<const float4*>(in) + i * 2;
  float4 a = p[0], b = p[1];
  f16x8 o;
  o[0] = (_Float16)a.x; o[1] = (_Float16)a.y; o[2] = (_Float16)a.z; o[3] = (_Float16)a.w;
  o[4] = (_Float16)b.x; o[5] = (_Float16)b.y; o[6] = (_Float16)b.z; o[7] = (_Float16)b.w;
  *reinterpret_cast<f16x8*>(out + base) = o;
}

// ---------------- conv + gating: y = Cg * causal_conv3(Bg * x) ----------------
__global__ __launch_bounds__(256) void conv_gate(const _Float16* __restrict__ BCx,
                                                 const float* __restrict__ Wc,   // [2048,1,3]
                                                 _Float16* __restrict__ Y) {
  const int h0 = threadIdx.x * 8;
  const int r0 = blockIdx.x * 8;
  const int s0 = r0 & 4095;

  float w0[8], w1[8], w2[8];
#pragma unroll
  for (int j = 0; j < 8; ++j) {
    w0[j] = Wc[(h0 + j) * 3 + 0];
    w1[j] = Wc[(h0 + j) * 3 + 1];
    w2[j] = Wc[(h0 + j) * 3 + 2];
  }

  float bxm2[8] = {}, bxm1[8] = {};
  if (s0 != 0) {
    const _Float16* pm2 = BCx + (size_t)(r0 - 2) * 6144 + h0;
    const _Float16* pm1 = BCx + (size_t)(r0 - 1) * 6144 + h0;
    f16x8 bg2 = *reinterpret_cast<const f16x8*>(pm2);
    f16x8 xx2 = *reinterpret_cast<const f16x8*>(pm2 + 4096);
    f16x8 bg1 = *reinterpret_cast<const f16x8*>(pm1);
    f16x8 xx1 = *reinterpret_cast<const f16x8*>(pm1 + 4096);
#pragma unroll
    for (int j = 0; j < 8; ++j) {
      bxm2[j] = (float)bg2[j] * (float)xx2[j];
      bxm1[j] = (float)bg1[j] * (float)xx1[j];
    }
  }

  for (int i = 0; i < 8; ++i) {
    const _Float16* pr = BCx + (size_t)(r0 + i) * 6144 + h0;
    f16x8 bg = *reinterpret_cast<const f16x8*>(pr);
    f16x8 cg = *reinterpret_cast<const f16x8*>(pr + 2048);
    f16x8 xx = *reinterpret_cast<const f16x8*>(pr + 4096);
    f16x8 o;
#pragma unroll
    for (int j = 0; j < 8; ++j) {
      float bx   = (float)bg[j] * (float)xx[j];
      float conv = w0[j] * bxm2[j] + w1[j] * bxm1[j] + w2[j] * bx;
      o[j] = (_Float16)((float)cg[j] * conv);
      bxm2[j] = bxm1[j];
      bxm1[j] = bx;
    }
    *reinterpret_cast<f16x8*>(Y + (size_t)(r0 + i) * 2048 + h0) = o;
  }
}

// ---------------- 32x32x16 fragment helpers ----------------
// A/B operand layout (analog of verified 16x16x32): row = lane&31, k = (lane>>5)*8 + e.
__device__ __forceinline__ void ldA32(f16x8 (&af)[2][4], const _Float16* p, int base,
                                      const int (&akc)[4]) {
#pragma unroll
  for (int f = 0; f < 2; ++f)
#pragma unroll
    for (int ks = 0; ks < 4; ++ks)
      af[f][ks] = *(const f16x8*)(p + base + f * 2048 + akc[ks]);
}
__device__ __forceinline__ void ldB32(f16x8 (&bf)[4], const _Float16* p, int base,
                                      const int (&akc)[4]) {
#pragma unroll
  for (int ks = 0; ks < 4; ++ks)
    bf[ks] = *(const f16x8*)(p + base + akc[ks]);
}
template <int QM, int QN>
__device__ __forceinline__ void mfmaQ32(f32x16 (&acc)[4][2], const f16x8 (&af)[2][4],
                                        const f16x8 (&bf)[4]) {
  __builtin_amdgcn_s_setprio(1);
#pragma unroll
  for (int ks = 0; ks < 4; ++ks)
#pragma unroll
    for (int f = 0; f < 2; ++f)
      acc[QM * 2 + f][QN] =
          __builtin_amdgcn_mfma_f32_32x32x16_f16(af[f][ks], bf[ks], acc[QM * 2 + f][QN], 0, 0, 0);
  __builtin_amdgcn_s_setprio(0);
}

// 256x256 NT GEMM, BK=64, 8 waves (2x4), per-wave 128x64, 32x32x16 MFMA.
// LDS: [256 rows][64 k] fp16 per operand, phys 16B-chunk ^= (row&7)  [T2].
// Staging: gld_lds linear dest + inverse-swizzled per-lane SOURCE (rule 21).
// Single-barrier phase: {reads; stage; vmcnt(4); BAR; lgkmcnt(0); sched0; MFMA}.
// Ledger: stage order P0:A'{0,2} P1:B'{0,1} P2:B'{2,3} P3:A'{1,3}; vmcnt(4) at
// P0/P1/P3 retires exactly the 4 units the NEXT phase reads, before the barrier
// that publishes them. Anti-hazard: every stage overwrites rows whose last read
// retired >=1 barrier earlier (audited per unit-class).
template <typename CT>
__global__ __launch_bounds__(512, 2) void gemm8p(const _Float16* __restrict__ Ag,
                                                 const _Float16* __restrict__ Bg,
                                                 CT* __restrict__ Cg,
                                                 int N, int K, int nbn) {
  __shared__ __align__(16) char smem[131072];
  const int tid = threadIdx.x, lane = tid & 63, w = tid >> 6;
  const int wr = w >> 2, wc = w & 3;

  // T1: XCD-bijective block swizzle (grid % 8 == 0)
  const int nwg = (int)gridDim.x, q8 = nwg >> 3;
  const int swz = ((int)blockIdx.x & 7) * q8 + ((int)blockIdx.x >> 3);
  const int bm = (swz / nbn) << 8, bn = (swz % nbn) << 8;

  _Float16* const A0 = (_Float16*)(smem);
  _Float16* const B0 = (_Float16*)(smem + 32768);
  _Float16* const A1 = (_Float16*)(smem + 65536);
  _Float16* const B1 = (_Float16*)(smem + 98304);

  const int rr = tid >> 3;
  const int sCol = ((tid & 7) ^ (rr & 7)) * 8;                  // inverse-swizzled source chunk
  const _Float16* aSrc = Ag + (size_t)(bm + rr) * K + sCol;
  const _Float16* bSrc = Bg + (size_t)(bn + (rr >> 5) * 64 + (rr & 31)) * K + sCol;

  // 32x32 fragment addressing; row&7 == lane&7 for all read rows -> chunk ^= lane&7
  int akc[4];
#pragma unroll
  for (int ks = 0; ks < 4; ++ks)
    akc[ks] = ((ks * 2 + (lane >> 5)) ^ (lane & 7)) * 8;
  const int aRB = (wr * 128 + (lane & 31)) * 64;   // A m-frags: +f*2048, QM: +4096
  const int bRB = (wc * 32 + (lane & 31)) * 64;    // B frag0; frag1: +8192

  const int nt = K >> 6;

#define STG_A(NBO, kt, u) GLD_LDS16(aSrc + (size_t)(u) * 64 * K + (kt) * 64, \
                                    smem + (NBO) + (u) * 8192 + tid * 16)
#define STG_B(NBO, kt, u) GLD_LDS16(bSrc + (size_t)(((u) & 1) * 128 + ((u) >> 1) * 32) * K + (kt) * 64, \
                                    smem + (NBO) + 32768 + (u) * 8192 + tid * 16)

  f16x8 af[2][4];
  f16x8 bf[4];
  f32x16 acc[4][2] = {};

  // prologue: tile 0 -> buffer 0, consumption order A0,A2,B0,B1 | B2,B3,A1,A3
  STG_A(0, 0, 0); STG_A(0, 0, 2);
  STG_B(0, 0, 0); STG_B(0, 0, 1);
  STG_B(0, 0, 2); STG_B(0, 0, 3);
  STG_A(0, 0, 1); STG_A(0, 0, 3);
  VMCNT4; BAR;

#define TILE(AB, BB, NBO, t)                                       \
  {                                                                \
    const int tn = ((t) + 1 < nt) ? (t) + 1 : nt - 1;              \
    /* P0: QM=0,QN=0 */                                            \
    ldA32(af, AB, aRB, akc);                                       \
    ldB32(bf, BB, bRB, akc);                                       \
    STG_A(NBO, tn, 0); STG_A(NBO, tn, 2);                          \
    VMCNT4; BAR; LGKM0; SCHED0;                                    \
    mfmaQ32<0, 0>(acc, af, bf);                                    \
    /* P1: QM=0,QN=1 */                                            \
    ldB32(bf, BB, bRB + 8192, akc);                                \
    STG_B(NBO, tn, 0); STG_B(NBO, tn, 1);                          \
    VMCNT4; BAR; LGKM0; SCHED0;                                    \
    mfmaQ32<0, 1>(acc, af, bf);                                    \
    /* P2: QM=1,QN=1 (bf frag1 kept) */                            \
    ldA32(af, AB, aRB + 4096, akc);                                \
    STG_B(NBO, tn, 2); STG_B(NBO, tn, 3);                          \
    BAR; LGKM0; SCHED0;                                            \
    mfmaQ32<1, 1>(acc, af, bf);                                    \
    /* P3: QM=1,QN=0 (re-read B frag0) */                          \
    ldB32(bf, BB, bRB, akc);                                       \
    STG_A(NBO, tn, 1); STG_A(NBO, tn, 3);                          \
    VMCNT4; BAR; LGKM0; SCHED0;                                    \
    mfmaQ32<1, 0>(acc, af, bf);                                    \
  }

  for (int t = 0; t < nt; t += 2) {
    TILE(A0, B0, 65536, t);
    TILE(A1, B1, 0, t + 1);
  }
  VMCNT0;  // drain LDS-DMA (tail restage never consumed)

  // epilogue: D col = lane&31, row = (reg&3) + 8*(reg>>2) + 4*(lane>>5)
  const int cb0 = bn + wc * 64 + (lane & 31);
  const int rb0 = bm + wr * 128 + 4 * (lane >> 5);
#pragma unroll
  for (int mf = 0; mf < 4; ++mf)
#pragma unroll
    for (int nf = 0; nf < 2; ++nf) {
      f32x16 v = acc[mf][nf];
      const int col = cb0 + nf * 32;
      const int rb  = rb0 + mf * 32;
#pragma unroll
      for (int rg = 0; rg < 16; ++rg)
        Cg[(size_t)(rb + (rg & 3) + 8 * (rg >> 2)) * N + col] = (CT)v[rg];
    }
#undef TILE
#undef STG_A
#undef STG_B
}

// ---------------- launcher ----------------
extern "C" void kernel_launch(void* const* d_in, const int* in_sizes, int n_in,
                              void* d_out, int out_size, void* d_ws, size_t ws_size,
                              hipStream_t stream) {
  const float* X  = (const float*)d_in[0];  // [2,4096,2048]
  const float* Wi = (const float*)d_in[1];  // [6144,2048]
  const float* Wc = (const float*)d_in[2];  // [2048,1,3]
  const float* Wo = (const float*)d_in[3];  // [2048,2048]
  float* out = (float*)d_out;               // [2,4096,2048] fp32

  char* ws = (char*)d_ws;
  _Float16* Xh   = (_Float16*)(ws);                    // 33,554,432 B
  _Float16* Wih  = (_Float16*)(ws + 33554432);         // 25,165,824 B
  _Float16* Woh  = (_Float16*)(ws + 58720256);         //  8,388,608 B
  _Float16* BCxh = (_Float16*)(ws + 67108864);         // 100,663,296 B
  _Float16* Yh   = (_Float16*)(ws + 167772160);        // 33,554,432 B
  (void)ws_size; (void)in_sizes; (void)n_in; (void)out_size;

  cvt_f32_f16<<<dim3(16777216 / 2048), 256, 0, stream>>>(X,  Xh,  16777216);
  cvt_f32_f16<<<dim3(12582912 / 2048), 256, 0, stream>>>(Wi, Wih, 12582912);
  cvt_f32_f16<<<dim3( 4194304 / 2048), 256, 0, stream>>>(Wo, Woh,  4194304);

  // in_proj: [8192,2048] x [6144,2048]^T -> BCx fp16   (32 x 24 = 768 blocks)
  gemm8p<_Float16><<<dim3(768), 512, 0, stream>>>(Xh, Wih, BCxh, 6144, 2048, 24);

  conv_gate<<<dim3(1024), 256, 0, stream>>>(BCxh, Wc, Yh);

  // out_proj: [8192,2048] x [2048,2048]^T -> out fp32  (32 x 8 = 256 blocks; N=2048)
  gemm8p<float><<<dim3(256), 512, 0, stream>>>(Yh, Woh, out, 2048, 2048, 8);
}

// Round 7
// 302.080 us; speedup vs baseline: 1.1448x; 1.1448x over previous
//
#include <hip/hip_runtime.h>
#include <hip/hip_fp16.h>

// LFM2 short-conv block. Round 7: round-5's 256x256 16x16x32 GEMM with SINGLE-barrier
// phases (vmcnt(4) before BAR; lgkmcnt(0)+sched_barrier(0) after) -> MFMA(p) overlaps
// other waves' ds_reads(p+1). 32x32 MFMA abandoned: its 32-row fragment span forces
// 4-way LDS bank conflicts under the 8-chunk XOR swizzle (round-6 evidence).

typedef _Float16 f16x8 __attribute__((ext_vector_type(8)));
typedef float    f32x4 __attribute__((ext_vector_type(4)));

#define GLD_LDS16(gsrc, sdst) \
  __builtin_amdgcn_global_load_lds((const __attribute__((address_space(1))) void*)(gsrc), \
                                   (__attribute__((address_space(3))) void*)(sdst), 16, 0, 0)

#define VMCNT4 asm volatile("s_waitcnt vmcnt(4)" ::: "memory")
#define VMCNT0 asm volatile("s_waitcnt vmcnt(0)" ::: "memory")
#define LGKM0  asm volatile("s_waitcnt lgkmcnt(0)" ::: "memory")
#define BAR    __builtin_amdgcn_s_barrier()
#define SCHED0 __builtin_amdgcn_sched_barrier(0)

// ---------------- fp32 -> fp16 convert (8 elems/thread) ----------------
__global__ __launch_bounds__(256) void cvt_f32_f16(const float* __restrict__ in,
                                                   _Float16* __restrict__ out, int n) {
  int i = blockIdx.x * 256 + threadIdx.x;
  int base = i * 8;
  if (base >= n) return;
  const float4* p = reinterpret_cast<const float4*>(in) + i * 2;
  float4 a = p[0], b = p[1];
  f16x8 o;
  o[0] = (_Float16)a.x; o[1] = (_Float16)a.y; o[2] = (_Float16)a.z; o[3] = (_Float16)a.w;
  o[4] = (_Float16)b.x; o[5] = (_Float16)b.y; o[6] = (_Float16)b.z; o[7] = (_Float16)b.w;
  *reinterpret_cast<f16x8*>(out + base) = o;
}

// ---------------- conv + gating: y = Cg * causal_conv3(Bg * x) ----------------
__global__ __launch_bounds__(256) void conv_gate(const _Float16* __restrict__ BCx,
                                                 const float* __restrict__ Wc,   // [2048,1,3]
                                                 _Float16* __restrict__ Y) {
  const int h0 = threadIdx.x * 8;
  const int r0 = blockIdx.x * 8;
  const int s0 = r0 & 4095;

  float w0[8], w1[8], w2[8];
#pragma unroll
  for (int j = 0; j < 8; ++j) {
    w0[j] = Wc[(h0 + j) * 3 + 0];
    w1[j] = Wc[(h0 + j) * 3 + 1];
    w2[j] = Wc[(h0 + j) * 3 + 2];
  }

  float bxm2[8] = {}, bxm1[8] = {};
  if (s0 != 0) {
    const _Float16* pm2 = BCx + (size_t)(r0 - 2) * 6144 + h0;
    const _Float16* pm1 = BCx + (size_t)(r0 - 1) * 6144 + h0;
    f16x8 bg2 = *reinterpret_cast<const f16x8*>(pm2);
    f16x8 xx2 = *reinterpret_cast<const f16x8*>(pm2 + 4096);
    f16x8 bg1 = *reinterpret_cast<const f16x8*>(pm1);
    f16x8 xx1 = *reinterpret_cast<const f16x8*>(pm1 + 4096);
#pragma unroll
    for (int j = 0; j < 8; ++j) {
      bxm2[j] = (float)bg2[j] * (float)xx2[j];
      bxm1[j] = (float)bg1[j] * (float)xx1[j];
    }
  }

  for (int i = 0; i < 8; ++i) {
    const _Float16* pr = BCx + (size_t)(r0 + i) * 6144 + h0;
    f16x8 bg = *reinterpret_cast<const f16x8*>(pr);
    f16x8 cg = *reinterpret_cast<const f16x8*>(pr + 2048);
    f16x8 xx = *reinterpret_cast<const f16x8*>(pr + 4096);
    f16x8 o;
#pragma unroll
    for (int j = 0; j < 8; ++j) {
      float bx   = (float)bg[j] * (float)xx[j];
      float conv = w0[j] * bxm2[j] + w1[j] * bxm1[j] + w2[j] * bx;
      o[j] = (_Float16)((float)cg[j] * conv);
      bxm2[j] = bxm1[j];
      bxm1[j] = bx;
    }
    *reinterpret_cast<f16x8*>(Y + (size_t)(r0 + i) * 2048 + h0) = o;
  }
}

// ---------------- 8-phase 256x256 NT GEMM (static 128KB LDS) ----------------
__device__ __forceinline__ void ldA(f16x8 (&af)[4][2], const _Float16* p, int base, int ak0, int ak1) {
#pragma unroll
  for (int i = 0; i < 4; ++i) {
    af[i][0] = *(const f16x8*)(p + base + i * 1024 + ak0);
    af[i][1] = *(const f16x8*)(p + base + i * 1024 + ak1);
  }
}
__device__ __forceinline__ void ldB(f16x8 (&bf)[2][2], const _Float16* p, int base, int ak0, int ak1) {
#pragma unroll
  for (int j = 0; j < 2; ++j) {
    bf[j][0] = *(const f16x8*)(p + base + j * 1024 + ak0);
    bf[j][1] = *(const f16x8*)(p + base + j * 1024 + ak1);
  }
}
template <int QM, int QN>
__device__ __forceinline__ void mfmaQ(f32x4 (&acc)[8][4], const f16x8 (&af)[4][2], const f16x8 (&bf)[2][2]) {
  __builtin_amdgcn_s_setprio(1);
#pragma unroll
  for (int i = 0; i < 4; ++i)
#pragma unroll
    for (int j = 0; j < 2; ++j)
#pragma unroll
      for (int ks = 0; ks < 2; ++ks)
        acc[QM * 4 + i][QN * 2 + j] =
            __builtin_amdgcn_mfma_f32_16x16x32_f16(af[i][ks], bf[j][ks], acc[QM * 4 + i][QN * 2 + j], 0, 0, 0);
  __builtin_amdgcn_s_setprio(0);
}

// A LDS: [256 rows][64 k] fp16, phys 16B-chunk ^= (row&7)  [T2 swizzle]
// Staging: gld_lds linear dest + inverse-swizzled per-lane SOURCE (rule 21).
// Single-barrier phase: {reads(p); stage; vmcnt(4); BAR; lgkmcnt(0); sched0; MFMA(p)}.
// Ledger (per-wave FIFO, 2 DMA/phase): vmcnt(4) leaves only the last 2 phases'
// stages outstanding -> units read next phase (staged 4 phases ago) retired >=2
// barriers before the read. Overwrite hazard: each stage targets units whose last
// readers completed their ds_reads before an earlier barrier (audited per class).
// Round-6 passed validation with this exact structure -> empirically race-free.
// ARGS: N = C column count/stride, K = reduction dim, nbn = N/256.
template <typename CT>
__global__ __launch_bounds__(512, 2) void gemm8p(const _Float16* __restrict__ Ag,
                                                 const _Float16* __restrict__ Bg,
                                                 CT* __restrict__ Cg,
                                                 int N, int K, int nbn) {
  __shared__ __align__(16) char smem[131072];
  const int tid = threadIdx.x, lane = tid & 63, w = tid >> 6;
  const int wr = w >> 2, wc = w & 3;

  // T1: XCD-bijective block swizzle (grid % 8 == 0)
  const int nwg = (int)gridDim.x, q8 = nwg >> 3;
  const int swz = ((int)blockIdx.x & 7) * q8 + ((int)blockIdx.x >> 3);
  const int bm = (swz / nbn) << 8, bn = (swz % nbn) << 8;

  _Float16* const A0 = (_Float16*)(smem);
  _Float16* const B0 = (_Float16*)(smem + 32768);
  _Float16* const A1 = (_Float16*)(smem + 65536);
  _Float16* const B1 = (_Float16*)(smem + 98304);

  const int rr = tid >> 3;
  const int sCol = ((tid & 7) ^ (rr & 7)) * 8;                  // inverse-swizzled source chunk
  const _Float16* aSrc = Ag + (size_t)(bm + rr) * K + sCol;
  const _Float16* bSrc = Bg + (size_t)(bn + (rr >> 5) * 64 + (rr & 31)) * K + sCol;

  // read-side swizzle folds to per-lane constants (row&7 == lane&7 for all read rows)
  const int ak0 = ((lane >> 4) ^ (lane & 7)) * 8;
  const int ak1 = (((lane >> 4) + 4) ^ (lane & 7)) * 8;
  const int aRB = (wr * 128 + (lane & 15)) * 64;
  const int bRB = (wc * 32 + (lane & 15)) * 64;

  const int nt = K >> 6;

#define STG_A(NBO, kt, u) GLD_LDS16(aSrc + (size_t)(u) * 64 * K + (kt) * 64, \
                                    smem + (NBO) + (u) * 8192 + tid * 16)
#define STG_B(NBO, kt, u) GLD_LDS16(bSrc + (size_t)(((u) & 1) * 128 + ((u) >> 1) * 32) * K + (kt) * 64, \
                                    smem + (NBO) + 32768 + (u) * 8192 + tid * 16)

  f16x8 af[4][2], bf[2][2];
  f32x4 acc[8][4] = {};

  // prologue: tile 0 -> buffer 0, consumption order A0,A2,B0,B1 | B2,B3,A1,A3
  STG_A(0, 0, 0); STG_A(0, 0, 2);
  STG_B(0, 0, 0); STG_B(0, 0, 1);
  STG_B(0, 0, 2); STG_B(0, 0, 3);
  STG_A(0, 0, 1); STG_A(0, 0, 3);
  VMCNT4; BAR;

  // Per tile: 4 single-barrier phases = C-quadrants (0,0),(0,1),(1,1),(1,0).
  // Stage slots consumption-ordered: P0:A'{0,2} P1:B'{0,1} P2:B'{2,3} P3:A'{1,3}.
#define TILE(AB, BB, NBO, t)                                       \
  {                                                                \
    const int tn = ((t) + 1 < nt) ? (t) + 1 : nt - 1;              \
    /* P0: q=(0,0) */                                              \
    ldA(af, AB, aRB, ak0, ak1);                                    \
    ldB(bf, BB, bRB, ak0, ak1);                                    \
    STG_A(NBO, tn, 0); STG_A(NBO, tn, 2);                          \
    VMCNT4; BAR; LGKM0; SCHED0;                                    \
    mfmaQ<0, 0>(acc, af, bf);                                      \
    /* P1: q=(0,1) */                                              \
    ldB(bf, BB, bRB + 8192, ak0, ak1);                             \
    STG_B(NBO, tn, 0); STG_B(NBO, tn, 1);                          \
    VMCNT4; BAR; LGKM0; SCHED0;                                    \
    mfmaQ<0, 1>(acc, af, bf);                                      \
    /* P2: q=(1,1) */                                              \
    ldA(af, AB, aRB + 4096, ak0, ak1);                             \
    STG_B(NBO, tn, 2); STG_B(NBO, tn, 3);                          \
    BAR; LGKM0; SCHED0;                                            \
    mfmaQ<1, 1>(acc, af, bf);                                      \
    /* P3: q=(1,0), re-read B half 0 */                            \
    ldB(bf, BB, bRB, ak0, ak1);                                    \
    STG_A(NBO, tn, 1); STG_A(NBO, tn, 3);                          \
    VMCNT4; BAR; LGKM0; SCHED0;                                    \
    mfmaQ<1, 0>(acc, af, bf);                                      \
  }

  for (int t = 0; t < nt; t += 2) {
    TILE(A0, B0, 65536, t);
    TILE(A1, B1, 0, t + 1);
  }
  VMCNT0;  // drain LDS-DMA (tail restage never consumed)

  // epilogue: D row=(lane>>4)*4+reg, col=lane&15
  const int rb = bm + wr * 128 + ((lane >> 4) << 2);
  const int cb = bn + wc * 64 + (lane & 15);
#pragma unroll
  for (int mi = 0; mi < 8; ++mi)
#pragma unroll
    for (int nj = 0; nj < 4; ++nj) {
      f32x4 v = acc[mi][nj];
#pragma unroll
      for (int rg = 0; rg < 4; ++rg)
        Cg[(size_t)(rb + mi * 16 + rg) * N + cb + nj * 16] = (CT)v[rg];
    }
#undef TILE
#undef STG_A
#undef STG_B
}

// ---------------- launcher ----------------
extern "C" void kernel_launch(void* const* d_in, const int* in_sizes, int n_in,
                              void* d_out, int out_size, void* d_ws, size_t ws_size,
                              hipStream_t stream) {
  const float* X  = (const float*)d_in[0];  // [2,4096,2048]
  const float* Wi = (const float*)d_in[1];  // [6144,2048]
  const float* Wc = (const float*)d_in[2];  // [2048,1,3]
  const float* Wo = (const float*)d_in[3];  // [2048,2048]
  float* out = (float*)d_out;               // [2,4096,2048] fp32

  char* ws = (char*)d_ws;
  _Float16* Xh   = (_Float16*)(ws);                    // 33,554,432 B
  _Float16* Wih  = (_Float16*)(ws + 33554432);         // 25,165,824 B
  _Float16* Woh  = (_Float16*)(ws + 58720256);         //  8,388,608 B
  _Float16* BCxh = (_Float16*)(ws + 67108864);         // 100,663,296 B
  _Float16* Yh   = (_Float16*)(ws + 167772160);        // 33,554,432 B
  (void)ws_size; (void)in_sizes; (void)n_in; (void)out_size;

  cvt_f32_f16<<<dim3(16777216 / 2048), 256, 0, stream>>>(X,  Xh,  16777216);
  cvt_f32_f16<<<dim3(12582912 / 2048), 256, 0, stream>>>(Wi, Wih, 12582912);
  cvt_f32_f16<<<dim3( 4194304 / 2048), 256, 0, stream>>>(Wo, Woh,  4194304);

  // in_proj: [8192,2048] x [6144,2048]^T -> BCx fp16   (32 x 24 = 768 blocks)
  gemm8p<_Float16><<<dim3(768), 512, 0, stream>>>(Xh, Wih, BCxh, 6144, 2048, 24);

  conv_gate<<<dim3(1024), 256, 0, stream>>>(BCxh, Wc, Yh);

  // out_proj: [8192,2048] x [2048,2048]^T -> out fp32  (32 x 8 = 256 blocks; N=2048)
  gemm8p<float><<<dim3(256), 512, 0, stream>>>(Yh, Woh, out, 2048, 2048, 8);
}